// Round 1
// baseline (996.204 us; speedup 1.0000x reference)
//
#include <hip/hip_runtime.h>
#include <hip/hip_bf16.h>

typedef unsigned short u16;
typedef __attribute__((ext_vector_type(4))) float f32x4;
typedef __attribute__((ext_vector_type(8))) short bf16x8;

#define BZ 64
#define LSEQ 2048
#define DDIM 512
#define UDIM 512
#define ADIM 512
#define KCH 64
#define VOC 32000
#define EDIM 256

__device__ __forceinline__ u16 f2bf(float f) {
    union { float f; unsigned int u; } v; v.f = f;
    unsigned int u = v.u;
    unsigned int r = (u + 0x7FFFu + ((u >> 16) & 1u)) >> 16;
    return (u16)r;
}

__device__ __forceinline__ float fast_tanh(float x) {
    x = fminf(fmaxf(x, -15.f), 15.f);
    float e = __expf(2.f * x);
    return (e - 1.f) * __frcp_rn(e + 1.f);
}

// ---------------- zero init for accumulated buffers ----------------
__global__ void zero_k(float* Ey, float* ctx) {
    int i = blockIdx.x * 256 + threadIdx.x;
    if (i < BZ * EDIM) Ey[i] = 0.f;
    if (i < BZ * UDIM) ctx[i] = 0.f;
}

// ---------------- multi-job tiled transpose + fp32->bf16 pack ----------------
#define MAXTJ 16
struct TJob { const float* src; u16* dst; int R, C, ld, tileEnd; };
struct TArgs { TJob j[MAXTJ]; int nj; };

__global__ __launch_bounds__(256) void transpose_pack(TArgs a) {
    __shared__ float ts[32][33];
    int bid = blockIdx.x;
    int ji = 0;
    while (bid >= a.j[ji].tileEnd) ji++;
    int tstart = ji ? a.j[ji - 1].tileEnd : 0;
    int local = bid - tstart;
    TJob J = a.j[ji];
    int tilesC = J.C >> 5;
    int tr = local / tilesC, tc = local - tr * tilesC;
    int r0 = tr << 5, c0 = tc << 5;
    int t = threadIdx.x, col = t & 31, row0 = t >> 5;
    #pragma unroll
    for (int i = 0; i < 4; i++) {
        int r = row0 + i * 8;
        ts[r][col] = J.src[(size_t)(r0 + r) * J.C + c0 + col];
    }
    __syncthreads();
    #pragma unroll
    for (int i = 0; i < 4; i++) {
        int crow = row0 + i * 8;
        J.dst[(size_t)(c0 + crow) * J.ld + r0 + col] = f2bf(ts[col][crow]);
    }
}

// ---------------- pack prev_target + prev_hidden to bf16 ----------------
__global__ void pack_misc(const float* __restrict__ pt, const float* __restrict__ ph,
                          u16* __restrict__ ptb, u16* __restrict__ phb) {
    int idx = blockIdx.x * 256 + threadIdx.x;
    if (idx < BZ * VOC) ptb[idx] = f2bf(pt[idx]);
    int i2 = idx - BZ * VOC;
    if (i2 >= 0 && i2 < BZ * UDIM) phb[i2] = f2bf(ph[i2]);
}

// ---------------- Conv1D (SAME, width 7) ----------------
__global__ __launch_bounds__(256) void conv_k(const float* __restrict__ Bm,
                                              const float* __restrict__ Qk,
                                              float* __restrict__ F) {
    int b = blockIdx.y, lb = blockIdx.x;
    int t = threadIdx.x, c = t & 63, lq = t >> 6;
    __shared__ float qs[7 * 64];
    __shared__ float bs[10];
    if (t < 448) qs[t] = Qk[t];
    int l0 = lb * 4;
    if (t < 10) {
        int l = l0 - 3 + t;
        bs[t] = (l >= 0 && l < LSEQ) ? Bm[b * LSEQ + l] : 0.f;
    }
    __syncthreads();
    float s = 0.f;
    #pragma unroll
    for (int w2 = 0; w2 < 7; w2++) s += bs[lq + w2] * qs[w2 * 64 + c];
    F[((size_t)(b * LSEQ + l0 + lq)) * 64 + c] = s;
}

// ---------------- generic MFMA GEMM: C(64 x N) = act(A(64xK)@Bt^T + add + bias) ----------------
// A: bf16 [64][ldA]; Bt: bf16 [N][ldB] (pre-transposed: Bt[n][k] = W[k][n])
__global__ __launch_bounds__(256) void gemm_k(
    const u16* __restrict__ A, int ldA,
    const u16* __restrict__ Bt, int ldB,
    float* __restrict__ C, int ldC,
    const float* __restrict__ addM, int ldAdd,
    const float* __restrict__ bias,
    u16* __restrict__ Cbf, int ldCbf,
    int chunksPerBlock, int act, int useAtomic)
{
    __shared__ u16 As[64 * 40];
    __shared__ u16 Bs[128 * 40];
    int tid = threadIdx.x;
    int n0 = blockIdx.x * 128;
    int c0 = blockIdx.y * chunksPerBlock;
    int w = tid >> 6, lane = tid & 63, q = lane >> 4, cc = lane & 15;
    f32x4 acc[4][2];
    #pragma unroll
    for (int a = 0; a < 4; a++)
        #pragma unroll
        for (int bb = 0; bb < 2; bb++) acc[a][bb] = (f32x4)0.f;

    for (int ck = 0; ck < chunksPerBlock; ck++) {
        int k0 = (c0 + ck) * 32;
        {
            int r = tid >> 2, seg = tid & 3;
            uint4 v = *(const uint4*)(A + (size_t)r * ldA + k0 + seg * 8);
            *(uint4*)&As[r * 40 + seg * 8] = v;
        }
        #pragma unroll
        for (int j = 0; j < 2; j++) {
            int idx = j * 256 + tid;
            int r = idx >> 2, seg = idx & 3;
            uint4 v = *(const uint4*)(Bt + (size_t)(n0 + r) * ldB + k0 + seg * 8);
            *(uint4*)&Bs[r * 40 + seg * 8] = v;
        }
        __syncthreads();
        bf16x8 af[4], bfr[2];
        #pragma unroll
        for (int mt = 0; mt < 4; mt++)
            af[mt] = *(const bf16x8*)&As[(mt * 16 + cc) * 40 + q * 8];
        #pragma unroll
        for (int nt = 0; nt < 2; nt++)
            bfr[nt] = *(const bf16x8*)&Bs[(w * 32 + nt * 16 + cc) * 40 + q * 8];
        #pragma unroll
        for (int mt = 0; mt < 4; mt++)
            #pragma unroll
            for (int nt = 0; nt < 2; nt++)
                acc[mt][nt] = __builtin_amdgcn_mfma_f32_16x16x32_bf16(af[mt], bfr[nt], acc[mt][nt], 0, 0, 0);
        __syncthreads();
    }
    #pragma unroll
    for (int mt = 0; mt < 4; mt++) {
        #pragma unroll
        for (int nt = 0; nt < 2; nt++) {
            #pragma unroll
            for (int r = 0; r < 4; r++) {
                int m = mt * 16 + q * 4 + r;
                int n = n0 + w * 32 + nt * 16 + cc;
                float v = acc[mt][nt][r];
                if (useAtomic) {
                    atomicAdd(&C[(size_t)m * ldC + n], v);
                } else {
                    if (addM) v += addM[(size_t)m * ldAdd + n];
                    if (bias) v += bias[n];
                    if (act == 1) v = 1.f / (1.f + expf(-v));
                    else if (act == 2) v = tanhf(v);
                    if (C) C[(size_t)m * ldC + n] = v;
                    if (Cbf) Cbf[(size_t)m * ldCbf + n] = f2bf(v);
                }
            }
        }
    }
}

// ---------------- attention score GEMM with fused tanh*Va reduction ----------------
// e[b,l] = sum_a tanh(hWa[b,a] + ([feat|F] @ [Ua;Uf])[l,a]) * Va[a]
__global__ __launch_bounds__(256) void attn_e_k(
    const float* __restrict__ feat, const float* __restrict__ F,
    const u16* __restrict__ Wt,       // [512][576] bf16, Wt[a][k]
    const float* __restrict__ hWa, const float* __restrict__ Va,
    float* __restrict__ e)
{
    __shared__ u16 As[64 * 40];
    __shared__ u16 Bs[512 * 40];
    __shared__ float red[4][64];
    int b = blockIdx.y, lt = blockIdx.x;
    int tid = threadIdx.x, w = tid >> 6, lane = tid & 63, q = lane >> 4, cc = lane & 15;
    const int l0 = lt * 64;
    f32x4 acc[4][8];
    #pragma unroll
    for (int a = 0; a < 4; a++)
        #pragma unroll
        for (int bb = 0; bb < 8; bb++) acc[a][bb] = (f32x4)0.f;

    for (int ck = 0; ck < 18; ck++) {
        int k0 = ck * 32;
        {
            int r = tid >> 2, seg = tid & 3;
            float4 f0, f1;
            if (ck < 16) {
                const float* p = feat + ((size_t)(b * LSEQ + l0 + r) * DDIM + k0 + seg * 8);
                f0 = *(const float4*)p; f1 = *(const float4*)(p + 4);
            } else {
                const float* p = F + ((size_t)(b * LSEQ + l0 + r) * 64 + (k0 - DDIM) + seg * 8);
                f0 = *(const float4*)p; f1 = *(const float4*)(p + 4);
            }
            u16 u[8] = { f2bf(f0.x), f2bf(f0.y), f2bf(f0.z), f2bf(f0.w),
                         f2bf(f1.x), f2bf(f1.y), f2bf(f1.z), f2bf(f1.w) };
            *(uint4*)&As[r * 40 + seg * 8] = *(uint4*)u;
        }
        #pragma unroll
        for (int j = 0; j < 8; j++) {
            int idx = j * 256 + tid;
            int r = idx >> 2, seg = idx & 3;
            uint4 v = *(const uint4*)(Wt + (size_t)r * 576 + k0 + seg * 8);
            *(uint4*)&Bs[r * 40 + seg * 8] = v;
        }
        __syncthreads();
        bf16x8 af[4];
        #pragma unroll
        for (int mt = 0; mt < 4; mt++)
            af[mt] = *(const bf16x8*)&As[(mt * 16 + cc) * 40 + q * 8];
        #pragma unroll
        for (int nt = 0; nt < 8; nt++) {
            bf16x8 bfr = *(const bf16x8*)&Bs[(w * 128 + nt * 16 + cc) * 40 + q * 8];
            #pragma unroll
            for (int mt = 0; mt < 4; mt++)
                acc[mt][nt] = __builtin_amdgcn_mfma_f32_16x16x32_bf16(af[mt], bfr, acc[mt][nt], 0, 0, 0);
        }
        __syncthreads();
    }
    const float* hb = hWa + b * ADIM;
    #pragma unroll
    for (int mt = 0; mt < 4; mt++) {
        #pragma unroll
        for (int r = 0; r < 4; r++) {
            float s = 0.f;
            #pragma unroll
            for (int nt = 0; nt < 8; nt++) {
                int a = w * 128 + nt * 16 + cc;
                s += fast_tanh(hb[a] + acc[mt][nt][r]) * Va[a];
            }
            s += __shfl_xor(s, 1, 16);
            s += __shfl_xor(s, 2, 16);
            s += __shfl_xor(s, 4, 16);
            s += __shfl_xor(s, 8, 16);
            if (cc == 0) red[w][mt * 16 + q * 4 + r] = s;
        }
    }
    __syncthreads();
    if (tid < 64)
        e[b * LSEQ + l0 + tid] = red[0][tid] + red[1][tid] + red[2][tid] + red[3][tid];
}

// ---------------- softmax over L per batch ----------------
__global__ __launch_bounds__(256) void softmaxL_k(const float* __restrict__ e,
                                                  float* __restrict__ attn_ws,
                                                  float* __restrict__ attn_out) {
    int b = blockIdx.x, t = threadIdx.x;
    __shared__ float sm[4], ss[4];
    float v[8];
    float mx = -1e30f;
    #pragma unroll
    for (int i = 0; i < 8; i++) { v[i] = e[b * LSEQ + t + i * 256]; mx = fmaxf(mx, v[i]); }
    for (int o = 32; o; o >>= 1) mx = fmaxf(mx, __shfl_xor(mx, o, 64));
    if ((t & 63) == 0) sm[t >> 6] = mx;
    __syncthreads();
    mx = fmaxf(fmaxf(sm[0], sm[1]), fmaxf(sm[2], sm[3]));
    float s = 0.f;
    #pragma unroll
    for (int i = 0; i < 8; i++) { v[i] = __expf(v[i] - mx); s += v[i]; }
    for (int o = 32; o; o >>= 1) s += __shfl_xor(s, o, 64);
    if ((t & 63) == 0) ss[t >> 6] = s;
    __syncthreads();
    s = ss[0] + ss[1] + ss[2] + ss[3];
    float inv = 1.f / s;
    #pragma unroll
    for (int i = 0; i < 8; i++) {
        float p = v[i] * inv;
        attn_ws[b * LSEQ + t + i * 256] = p;
        attn_out[b * LSEQ + t + i * 256] = p;
    }
}

// ---------------- context = sum_l attn * features ----------------
__global__ __launch_bounds__(256) void context_k(const float* __restrict__ feat,
                                                 const float* __restrict__ attn,
                                                 float* __restrict__ ctx) {
    int b = blockIdx.y, lc = blockIdx.x, t = threadIdx.x;
    __shared__ float as_[128];
    if (t < 128) as_[t] = attn[b * LSEQ + lc * 128 + t];
    __syncthreads();
    float c0 = 0.f, c1 = 0.f;
    const float* fp = feat + (size_t)(b * LSEQ + lc * 128) * DDIM;
    #pragma unroll 4
    for (int l = 0; l < 128; l++) {
        float av = as_[l];
        c0 += av * fp[(size_t)l * DDIM + t];
        c1 += av * fp[(size_t)l * DDIM + t + 256];
    }
    atomicAdd(&ctx[b * UDIM + t], c0);
    atomicAdd(&ctx[b * UDIM + t + 256], c1);
}

// ---------------- small pack / elementwise kernels ----------------
__global__ void pack_acat1_k(const float* __restrict__ Ey, const float* __restrict__ h,
                             const float* __restrict__ ctx, u16* __restrict__ Acat1,
                             const float* __restrict__ bwyh, const float* __restrict__ burh,
                             float* __restrict__ bsum) {
    int b = blockIdx.x, t = threadIdx.x;
    for (int col = t; col < 1280; col += 256) {
        float v = (col < 256) ? Ey[b * 256 + col]
                : (col < 768) ? h[b * 512 + col - 256]
                              : ctx[b * 512 + col - 768];
        Acat1[b * 1280 + col] = f2bf(v);
    }
    if (b == 0) { for (int i = t; i < 512; i += 256) bsum[i] = bwyh[i] + burh[i]; }
}

__global__ void pack_acath_k(const float* __restrict__ Ey, const float* __restrict__ rt,
                             const float* __restrict__ h, u16* __restrict__ AcatH) {
    int b = blockIdx.x, t = threadIdx.x;
    for (int col = t; col < 768; col += 256) {
        float v = (col < 256) ? Ey[b * 256 + col] : rt[b * 512 + col - 256] * h[b * 512 + col - 256];
        AcatH[b * 768 + col] = f2bf(v);
    }
}

__global__ void pack_ht3_k(const float* __restrict__ zt, const float* __restrict__ hc,
                           const float* __restrict__ h, const float* __restrict__ ctx,
                           float* __restrict__ ht_out, u16* __restrict__ Acat3) {
    int b = blockIdx.x, t = threadIdx.x;
    for (int u = t; u < 512; u += 256) {
        float z = zt[b * 512 + u];
        float v = (1.f - z) * h[b * 512 + u] + z * hc[b * 512 + u];
        ht_out[b * 512 + u] = v;
        Acat3[b * 1024 + u] = f2bf(v);
        Acat3[b * 1024 + 512 + u] = f2bf(ctx[b * 512 + u]);
    }
}

// ---------------- softmax over V ----------------
__global__ __launch_bounds__(1024) void softmaxV_k(const float* __restrict__ logits,
                                                   float* __restrict__ out) {
    int b = blockIdx.x, t = threadIdx.x;
    __shared__ float sm[16], ss[16];
    const float* lp = logits + (size_t)b * VOC;
    float mx = -1e30f;
    for (int i = t; i < VOC; i += 1024) mx = fmaxf(mx, lp[i]);
    for (int o = 32; o; o >>= 1) mx = fmaxf(mx, __shfl_xor(mx, o, 64));
    if ((t & 63) == 0) sm[t >> 6] = mx;
    __syncthreads();
    if (t < 16) {
        float m2 = sm[t];
        for (int o = 8; o; o >>= 1) m2 = fmaxf(m2, __shfl_xor(m2, o, 16));
        sm[t] = m2;
    }
    __syncthreads();
    mx = sm[0];
    float s = 0.f;
    for (int i = t; i < VOC; i += 1024) s += __expf(lp[i] - mx);
    for (int o = 32; o; o >>= 1) s += __shfl_xor(s, o, 64);
    if ((t & 63) == 0) ss[t >> 6] = s;
    __syncthreads();
    if (t < 16) {
        float s2 = ss[t];
        for (int o = 8; o; o >>= 1) s2 += __shfl_xor(s2, o, 16);
        ss[t] = s2;
    }
    __syncthreads();
    float inv = 1.f / ss[0];
    float* op = out + (size_t)b * VOC;
    for (int i = t; i < VOC; i += 1024) op[i] = __expf(lp[i] - mx) * inv;
}

// ---------------- workspace layout (bytes) ----------------
#define OFF_F       ((size_t)0)
#define OFF_WTCAT   ((size_t)33554432)
#define OFF_WTWA    ((size_t)34144256)
#define OFF_WTWE    ((size_t)34668544)
#define OFF_WTWO    ((size_t)51052544)
#define OFF_WTHC    ((size_t)67436544)
#define OFF_WTZ     ((size_t)67960832)
#define OFF_WTR     ((size_t)69271552)
#define OFF_WTH     ((size_t)70582272)
#define OFF_PTB     ((size_t)71368704)
#define OFF_PHB     ((size_t)75464704)
#define OFF_E       ((size_t)75530240)
#define OFF_ATTNWS  ((size_t)76054528)
#define OFF_HWA     ((size_t)76578816)
#define OFF_EY      ((size_t)76709888)
#define OFF_CTX     ((size_t)76775424)
#define OFF_ACAT1   ((size_t)76906496)
#define OFF_ZT      ((size_t)77070336)
#define OFF_RT      ((size_t)77201408)
#define OFF_CCZ     ((size_t)77332480)
#define OFF_HC      ((size_t)77463552)
#define OFF_ACATH   ((size_t)77594624)
#define OFF_ACAT3   ((size_t)77692928)
#define OFF_BSUM    ((size_t)77824000)
#define OFF_GF32    ((size_t)77826048)
#define OFF_GBF     ((size_t)77891584)
#define OFF_LOGITS  ((size_t)77924352)

extern "C" void kernel_launch(void* const* d_in, const int* in_sizes, int n_in,
                              void* d_out, int out_size, void* d_ws, size_t ws_size,
                              hipStream_t stream)
{
    const float* prev_target = (const float*)d_in[0];
    const float* prev_hidden = (const float*)d_in[1];
    const float* features    = (const float*)d_in[2];
    const float* Bmat        = (const float*)d_in[3];
    const float* Wa    = (const float*)d_in[4];
    const float* Ua    = (const float*)d_in[5];
    const float* Va    = (const float*)d_in[6];
    const float* Uf    = (const float*)d_in[7];
    const float* Qk    = (const float*)d_in[8];
    const float* We    = (const float*)d_in[9];
    const float* Wccz  = (const float*)d_in[10];
    const float* Wyz   = (const float*)d_in[11];
    const float* Uhz   = (const float*)d_in[12];
    const float* Wyr   = (const float*)d_in[13];
    const float* Uhr   = (const float*)d_in[14];
    const float* Ccr   = (const float*)d_in[15];
    const float* Wyh   = (const float*)d_in[16];
    const float* b_wyh = (const float*)d_in[17];
    const float* Urh   = (const float*)d_in[18];
    const float* b_urh = (const float*)d_in[19];
    const float* Wo    = (const float*)d_in[20];
    const float* Wh    = (const float*)d_in[21];
    const float* Wc    = (const float*)d_in[22];

    char* w = (char*)d_ws;
    float* F_buf    = (float*)(w + OFF_F);
    u16*   Wt_cat   = (u16*)(w + OFF_WTCAT);
    u16*   Wt_wa    = (u16*)(w + OFF_WTWA);
    u16*   Wt_we    = (u16*)(w + OFF_WTWE);
    u16*   Wt_wo    = (u16*)(w + OFF_WTWO);
    u16*   Wt_hc    = (u16*)(w + OFF_WTHC);
    u16*   Wt_z     = (u16*)(w + OFF_WTZ);
    u16*   Wt_r     = (u16*)(w + OFF_WTR);
    u16*   Wt_h     = (u16*)(w + OFF_WTH);
    u16*   pt_bf    = (u16*)(w + OFF_PTB);
    u16*   ph_bf    = (u16*)(w + OFF_PHB);
    float* e_buf    = (float*)(w + OFF_E);
    float* attn_ws  = (float*)(w + OFF_ATTNWS);
    float* hWa_buf  = (float*)(w + OFF_HWA);
    float* Ey_buf   = (float*)(w + OFF_EY);
    float* ctx_buf  = (float*)(w + OFF_CTX);
    u16*   Acat1    = (u16*)(w + OFF_ACAT1);
    float* zt_buf   = (float*)(w + OFF_ZT);
    float* rt_buf   = (float*)(w + OFF_RT);
    float* ccz_buf  = (float*)(w + OFF_CCZ);
    float* hc_buf   = (float*)(w + OFF_HC);
    u16*   AcatH    = (u16*)(w + OFF_ACATH);
    u16*   Acat3    = (u16*)(w + OFF_ACAT3);
    float* bsum     = (float*)(w + OFF_BSUM);
    float* Gf32     = (float*)(w + OFF_GF32);
    u16*   Gbf      = (u16*)(w + OFF_GBF);
    float* logits   = (float*)(w + OFF_LOGITS);

    float* out      = (float*)d_out;
    float* ht_out   = out + (size_t)BZ * VOC;
    float* attn_out = ht_out + (size_t)BZ * UDIM;

    // transpose jobs
    TArgs ta;
    int cum = 0, ji = 0;
    auto addJob = [&](const float* src, u16* dst, int R, int C, int ld) {
        cum += (R / 32) * (C / 32);
        ta.j[ji].src = src; ta.j[ji].dst = dst;
        ta.j[ji].R = R; ta.j[ji].C = C; ta.j[ji].ld = ld; ta.j[ji].tileEnd = cum;
        ji++;
    };
    addJob(Ua,   Wt_cat + 0,   512, 512, 576);
    addJob(Uf,   Wt_cat + 512,  64, 512, 576);
    addJob(Wa,   Wt_wa,        512, 512, 512);
    addJob(We,   Wt_we,      32000, 256, 32000);
    addJob(Wo,   Wt_wo,        256, 32000, 256);
    addJob(Wh,   Wt_hc + 0,    512, 256, 1024);
    addJob(Wc,   Wt_hc + 512,  512, 256, 1024);
    addJob(Wyz,  Wt_z + 0,     256, 512, 1280);
    addJob(Uhz,  Wt_z + 256,   512, 512, 1280);
    addJob(Wccz, Wt_z + 768,   512, 512, 1280);
    addJob(Wyr,  Wt_r + 0,     256, 512, 1280);
    addJob(Uhr,  Wt_r + 256,   512, 512, 1280);
    addJob(Ccr,  Wt_r + 768,   512, 512, 1280);
    addJob(Wyh,  Wt_h + 0,     256, 512, 768);
    addJob(Urh,  Wt_h + 256,   512, 512, 768);
    ta.nj = ji;

    hipLaunchKernelGGL(zero_k, dim3(128), dim3(256), 0, stream, Ey_buf, ctx_buf);
    hipLaunchKernelGGL(transpose_pack, dim3(cum), dim3(256), 0, stream, ta);
    hipLaunchKernelGGL(pack_misc, dim3(8128), dim3(256), 0, stream,
                       prev_target, prev_hidden, pt_bf, ph_bf);
    hipLaunchKernelGGL(conv_k, dim3(512, 64), dim3(256), 0, stream, Bmat, Qk, F_buf);

    // hWa = prev_hidden @ Wa  (64x512, K=512)
    hipLaunchKernelGGL(gemm_k, dim3(4, 1), dim3(256), 0, stream,
                       ph_bf, 512, Wt_wa, 512, hWa_buf, 512,
                       (const float*)nullptr, 0, (const float*)nullptr, (u16*)nullptr, 0,
                       16, 0, 0);

    // attention scores e
    hipLaunchKernelGGL(attn_e_k, dim3(32, 64), dim3(256), 0, stream,
                       features, F_buf, Wt_cat, hWa_buf, Va, e_buf);
    hipLaunchKernelGGL(softmaxL_k, dim3(64), dim3(256), 0, stream, e_buf, attn_ws, attn_out);
    hipLaunchKernelGGL(context_k, dim3(16, 64), dim3(256), 0, stream, features, attn_ws, ctx_buf);

    // Ey = prev_target @ We (64x256, K=32000), split-K atomics
    hipLaunchKernelGGL(gemm_k, dim3(2, 125), dim3(256), 0, stream,
                       pt_bf, 32000, Wt_we, 32000, Ey_buf, 256,
                       (const float*)nullptr, 0, (const float*)nullptr, (u16*)nullptr, 0,
                       8, 0, 1);

    hipLaunchKernelGGL(pack_acat1_k, dim3(64), dim3(256), 0, stream,
                       Ey_buf, prev_hidden, ctx_buf, Acat1, b_wyh, b_urh, bsum);

    // zt, rt: sigmoid([Ey|h|ctx] @ Wt_{z,r}), K=1280
    hipLaunchKernelGGL(gemm_k, dim3(4, 1), dim3(256), 0, stream,
                       Acat1, 1280, Wt_z, 1280, zt_buf, 512,
                       (const float*)nullptr, 0, (const float*)nullptr, (u16*)nullptr, 0,
                       40, 1, 0);
    hipLaunchKernelGGL(gemm_k, dim3(4, 1), dim3(256), 0, stream,
                       Acat1, 1280, Wt_r, 1280, rt_buf, 512,
                       (const float*)nullptr, 0, (const float*)nullptr, (u16*)nullptr, 0,
                       40, 1, 0);
    // ccz = ctx @ Wccz (K=512), reuse Acat1 cols 768.. and Wt_z cols 768..
    hipLaunchKernelGGL(gemm_k, dim3(4, 1), dim3(256), 0, stream,
                       Acat1 + 768, 1280, Wt_z + 768, 1280, ccz_buf, 512,
                       (const float*)nullptr, 0, (const float*)nullptr, (u16*)nullptr, 0,
                       16, 0, 0);

    hipLaunchKernelGGL(pack_acath_k, dim3(64), dim3(256), 0, stream,
                       Ey_buf, rt_buf, prev_hidden, AcatH);

    // h_cand = tanh([Ey|rt*h] @ Wt_h + ccz + bsum), K=768
    hipLaunchKernelGGL(gemm_k, dim3(4, 1), dim3(256), 0, stream,
                       AcatH, 768, Wt_h, 768, hc_buf, 512,
                       ccz_buf, 512, bsum, (u16*)nullptr, 0,
                       24, 2, 0);

    hipLaunchKernelGGL(pack_ht3_k, dim3(64), dim3(256), 0, stream,
                       zt_buf, hc_buf, prev_hidden, ctx_buf, ht_out, Acat3);

    // G = Ey + [ht|ctx] @ [Wh;Wc], K=1024 -> bf16
    hipLaunchKernelGGL(gemm_k, dim3(2, 1), dim3(256), 0, stream,
                       Acat3, 1024, Wt_hc, 1024, Gf32, 256,
                       Ey_buf, 256, (const float*)nullptr, Gbf, 256,
                       32, 0, 0);

    // logits = G @ Wo (64x32000, K=256)
    hipLaunchKernelGGL(gemm_k, dim3(250, 1), dim3(256), 0, stream,
                       Gbf, 256, Wt_wo, 256, logits, 32000,
                       (const float*)nullptr, 0, (const float*)nullptr, (u16*)nullptr, 0,
                       8, 0, 0);

    hipLaunchKernelGGL(softmaxV_k, dim3(64), dim3(1024), 0, stream, logits, out);
}

// Round 3
// 726.495 us; speedup vs baseline: 1.3712x; 1.3712x over previous
//
#include <hip/hip_runtime.h>
#include <hip/hip_bf16.h>

typedef unsigned short u16;
typedef __attribute__((ext_vector_type(4))) float f32x4;
typedef __attribute__((ext_vector_type(8))) short bf16x8;

#define BZ 64
#define LSEQ 2048
#define DDIM 512
#define UDIM 512
#define ADIM 512
#define VOC 32000
#define EDIM 256

__device__ __forceinline__ u16 f2bf(float f) {
    union { float f; unsigned int u; } v; v.f = f;
    unsigned int u = v.u;
    return (u16)((u + 0x7FFFu + ((u >> 16) & 1u)) >> 16);
}

__device__ __forceinline__ float fast_tanh(float x) {
    x = fminf(fmaxf(x, -15.f), 15.f);
    float e = __expf(2.f * x);
    return (e - 1.f) * __frcp_rn(e + 1.f);
}

// BISECT (R3): global_load_lds staging replaced with explicit vector stores.
// Identical LDS layout (base + lane*16B). If this passes, R2's failure was the
// GLL path; reintroduce it one kernel at a time.
__device__ __forceinline__ void stage16(const u16* __restrict__ g, u16* l, int lane) {
    *(uint4*)(l + lane * 8) = *(const uint4*)g;
}

// ---------------- zero accumulators (contiguous region) ----------------
__global__ void zero_k(float4* p, int n) {
    int i = blockIdx.x * 256 + threadIdx.x;
    if (i < n) { float4 z; z.x = z.y = z.z = z.w = 0.f; p[i] = z; }
}

// ---------------- multi-job tiled transpose + fp32->bf16 pack ----------------
#define MAXTJ 16
struct TJob { const float* src; u16* dst; int R, C, ld, tileEnd; };
struct TArgs { TJob j[MAXTJ]; int nj; };

__global__ __launch_bounds__(256) void transpose_pack(TArgs a) {
    __shared__ float ts[32][33];
    int bid = blockIdx.x;
    int ji = 0;
    while (bid >= a.j[ji].tileEnd) ji++;
    int tstart = ji ? a.j[ji - 1].tileEnd : 0;
    int local = bid - tstart;
    TJob J = a.j[ji];
    int tilesC = J.C >> 5;
    int tr = local / tilesC, tc = local - tr * tilesC;
    int r0 = tr << 5, c0 = tc << 5;
    int t = threadIdx.x, col = t & 31, row0 = t >> 5;
    #pragma unroll
    for (int i = 0; i < 4; i++) {
        int r = row0 + i * 8;
        ts[r][col] = J.src[(size_t)(r0 + r) * J.C + c0 + col];
    }
    __syncthreads();
    #pragma unroll
    for (int i = 0; i < 4; i++) {
        int crow = row0 + i * 8;
        J.dst[(size_t)(c0 + crow) * J.ld + r0 + col] = f2bf(ts[col][crow]);
    }
}

// ---------------- pack prev_target + prev_hidden to bf16 ----------------
__global__ void pack_misc(const float* __restrict__ pt, const float* __restrict__ ph,
                          u16* __restrict__ ptb, u16* __restrict__ phb) {
    int idx = blockIdx.x * 256 + threadIdx.x;
    if (idx < BZ * VOC) ptb[idx] = f2bf(pt[idx]);
    int i2 = idx - BZ * VOC;
    if (i2 >= 0 && i2 < BZ * UDIM) phb[i2] = f2bf(ph[i2]);
}

// ---------------- prep: featbf[row][0..511]=bf16(feat), [512..575]=bf16(conv) ----------------
__global__ __launch_bounds__(256) void prep_feat_k(
    const float* __restrict__ feat, const float* __restrict__ Bm,
    const float* __restrict__ Qk, u16* __restrict__ featbf)
{
    __shared__ float qs[448];
    __shared__ float bwin[72];
    int t = threadIdx.x;
    int row0 = blockIdx.x * 64;
    int b = row0 >> 11, l0 = row0 & 2047;
    if (t < 448) qs[t] = Qk[t];
    if (t < 70) { int l = l0 - 3 + t; bwin[t] = (l >= 0 && l < LSEQ) ? Bm[b * LSEQ + l] : 0.f; }
    __syncthreads();
    // features part: 64 rows x 512 cols
    #pragma unroll
    for (int it = 0; it < 8; it++) {
        int r = it * 8 + (t >> 5), c = (t & 31) * 16;
        const float* p = feat + (size_t)(row0 + r) * DDIM + c;
        float4 a0 = *(const float4*)p, a1 = *(const float4*)(p + 4),
               a2 = *(const float4*)(p + 8), a3 = *(const float4*)(p + 12);
        u16 u[16] = { f2bf(a0.x), f2bf(a0.y), f2bf(a0.z), f2bf(a0.w),
                      f2bf(a1.x), f2bf(a1.y), f2bf(a1.z), f2bf(a1.w),
                      f2bf(a2.x), f2bf(a2.y), f2bf(a2.z), f2bf(a2.w),
                      f2bf(a3.x), f2bf(a3.y), f2bf(a3.z), f2bf(a3.w) };
        u16* dst = featbf + (size_t)(row0 + r) * 576 + c;
        *(uint4*)dst = *(uint4*)u;
        *(uint4*)(dst + 8) = *(uint4*)(u + 8);
    }
    // conv part: 64 rows x 64 cols; 4 threads/row, 16 cols each
    {
        int r = t >> 2, c = (t & 3) * 16;
        float s[16];
        #pragma unroll
        for (int j = 0; j < 16; j++) s[j] = 0.f;
        #pragma unroll
        for (int w7 = 0; w7 < 7; w7++) {
            float bv = bwin[r + w7];
            #pragma unroll
            for (int j = 0; j < 16; j++) s[j] += bv * qs[w7 * 64 + c + j];
        }
        u16 u[16];
        #pragma unroll
        for (int j = 0; j < 16; j++) u[j] = f2bf(s[j]);
        u16* dst = featbf + (size_t)(row0 + r) * 576 + 512 + c;
        *(uint4*)dst = *(uint4*)u;
        *(uint4*)(dst + 8) = *(uint4*)(u + 8);
    }
}

// ---------------- batched small GEMM: 64(M) x 64(N) tiles, split-K atomics ----------------
#define MAXGJ 4
struct GJob { const u16* A; const u16* Bt; float* C;
              int ldA, ldB, ldC, nT, ckPer, ckTot, tileEnd, store; };
struct GArgs { GJob j[MAXGJ]; };

__global__ __launch_bounds__(256) void gemm_batch_k(GArgs ga) {
    __shared__ u16 As[64 * 32];
    __shared__ u16 Bs[64 * 32];
    int bid = blockIdx.x, ji = 0;
    while (bid >= ga.j[ji].tileEnd) ji++;
    GJob J = ga.j[ji];
    int local = bid - (ji ? ga.j[ji - 1].tileEnd : 0);
    int nti = local % J.nT, ksi = local / J.nT;
    int n0 = nti * 64;
    int ck0 = ksi * J.ckPer;
    int ckEnd = ck0 + J.ckPer; if (ckEnd > J.ckTot) ckEnd = J.ckTot;
    int tid = threadIdx.x, w = tid >> 6, lane = tid & 63, q = lane >> 4, cc = lane & 15;
    int wrow = lane >> 2, wseg = lane & 3;
    f32x4 acc[4];
    #pragma unroll
    for (int mt = 0; mt < 4; mt++) acc[mt] = (f32x4)0.f;
    const u16* Ab = J.A + (size_t)(w * 16 + wrow) * J.ldA + wseg * 8;
    const u16* Bb = J.Bt + (size_t)(n0 + w * 16 + wrow) * J.ldB + wseg * 8;
    for (int ck = ck0; ck < ckEnd; ck++) {
        int k0 = ck * 32;
        stage16(Ab + k0, &As[w * 512], lane);
        stage16(Bb + k0, &Bs[w * 512], lane);
        __syncthreads();
        bf16x8 af[4];
        #pragma unroll
        for (int mt = 0; mt < 4; mt++)
            af[mt] = *(const bf16x8*)&As[(mt * 16 + cc) * 32 + q * 8];
        bf16x8 bfr = *(const bf16x8*)&Bs[(w * 16 + cc) * 32 + q * 8];
        #pragma unroll
        for (int mt = 0; mt < 4; mt++)
            acc[mt] = __builtin_amdgcn_mfma_f32_16x16x32_bf16(af[mt], bfr, acc[mt], 0, 0, 0);
        __syncthreads();
    }
    #pragma unroll
    for (int mt = 0; mt < 4; mt++) {
        #pragma unroll
        for (int rr = 0; rr < 4; rr++) {
            int m = mt * 16 + q * 4 + rr, n = n0 + w * 16 + cc;
            float v = acc[mt][rr];
            if (J.store) J.C[(size_t)m * J.ldC + n] = v;
            else atomicAdd(&J.C[(size_t)m * J.ldC + n], v);
        }
    }
}

// ---------------- attention GEMM (128x128 tile) + fused tanh*Va epilogue ----------------
__global__ __launch_bounds__(256) void attn_gemm_k(
    const u16* __restrict__ featbf, const u16* __restrict__ Wt,
    const float* __restrict__ hWa, const float* __restrict__ Va,
    float* __restrict__ e)
{
    __shared__ u16 As[128 * 32];
    __shared__ u16 Bs[128 * 32];
    int row0 = blockIdx.x * 128;
    int col0 = blockIdx.y * 128;
    int b = row0 >> 11;
    int tid = threadIdx.x, w = tid >> 6, lane = tid & 63, q = lane >> 4, cc = lane & 15;
    int wrow = lane >> 2, wseg = lane & 3;
    int rh = w & 1, ch = w >> 1;
    f32x4 acc[4][4];
    #pragma unroll
    for (int mt = 0; mt < 4; mt++)
        #pragma unroll
        for (int nt = 0; nt < 4; nt++) acc[mt][nt] = (f32x4)0.f;
    const u16* Abase = featbf + (size_t)row0 * 576 + wseg * 8;
    const u16* Bbase = Wt + (size_t)col0 * 576 + wseg * 8;
    for (int ck = 0; ck < 18; ck++) {
        int k0 = ck * 32;
        #pragma unroll
        for (int i = 0; i < 2; i++) {
            int rr = (i * 4 + w) * 16 + wrow;
            stage16(Abase + (size_t)rr * 576 + k0, &As[(i * 4 + w) * 512], lane);
            stage16(Bbase + (size_t)rr * 576 + k0, &Bs[(i * 4 + w) * 512], lane);
        }
        __syncthreads();
        bf16x8 af[4], bfr[4];
        #pragma unroll
        for (int mt = 0; mt < 4; mt++)
            af[mt] = *(const bf16x8*)&As[(rh * 64 + mt * 16 + cc) * 32 + q * 8];
        #pragma unroll
        for (int nt = 0; nt < 4; nt++)
            bfr[nt] = *(const bf16x8*)&Bs[(ch * 64 + nt * 16 + cc) * 32 + q * 8];
        #pragma unroll
        for (int mt = 0; mt < 4; mt++)
            #pragma unroll
            for (int nt = 0; nt < 4; nt++)
                acc[mt][nt] = __builtin_amdgcn_mfma_f32_16x16x32_bf16(af[mt], bfr[nt], acc[mt][nt], 0, 0, 0);
        __syncthreads();
    }
    float hv[4], vv[4];
    #pragma unroll
    for (int nt = 0; nt < 4; nt++) {
        int n = col0 + ch * 64 + nt * 16 + cc;
        hv[nt] = hWa[b * ADIM + n];
        vv[nt] = Va[n];
    }
    #pragma unroll
    for (int mt = 0; mt < 4; mt++) {
        #pragma unroll
        for (int rr = 0; rr < 4; rr++) {
            float s = 0.f;
            #pragma unroll
            for (int nt = 0; nt < 4; nt++)
                s += fast_tanh(hv[nt] + acc[mt][nt][rr]) * vv[nt];
            s += __shfl_xor(s, 1, 16);
            s += __shfl_xor(s, 2, 16);
            s += __shfl_xor(s, 4, 16);
            s += __shfl_xor(s, 8, 16);
            if (cc == 0)
                atomicAdd(&e[row0 + rh * 64 + mt * 16 + q * 4 + rr], s);
        }
    }
}

// ---------------- softmax over L per batch ----------------
__global__ __launch_bounds__(256) void softmaxL_k(const float* __restrict__ e,
                                                  float* __restrict__ attn_ws,
                                                  float* __restrict__ attn_out) {
    int b = blockIdx.x, t = threadIdx.x;
    __shared__ float sm[4], ss[4];
    float v[8];
    float mx = -1e30f;
    #pragma unroll
    for (int i = 0; i < 8; i++) { v[i] = e[b * LSEQ + t + i * 256]; mx = fmaxf(mx, v[i]); }
    for (int o = 32; o; o >>= 1) mx = fmaxf(mx, __shfl_xor(mx, o, 64));
    if ((t & 63) == 0) sm[t >> 6] = mx;
    __syncthreads();
    mx = fmaxf(fmaxf(sm[0], sm[1]), fmaxf(sm[2], sm[3]));
    float s = 0.f;
    #pragma unroll
    for (int i = 0; i < 8; i++) { v[i] = __expf(v[i] - mx); s += v[i]; }
    for (int o = 32; o; o >>= 1) s += __shfl_xor(s, o, 64);
    if ((t & 63) == 0) ss[t >> 6] = s;
    __syncthreads();
    s = ss[0] + ss[1] + ss[2] + ss[3];
    float inv = 1.f / s;
    #pragma unroll
    for (int i = 0; i < 8; i++) {
        float p = v[i] * inv;
        attn_ws[b * LSEQ + t + i * 256] = p;
        attn_out[b * LSEQ + t + i * 256] = p;
    }
}

// ---------------- context = sum_l attn * feat (bf16 source), L-split atomics ----------------
__global__ __launch_bounds__(256) void context2_k(
    const u16* __restrict__ featbf, const float* __restrict__ attn,
    float* __restrict__ ctx)
{
    __shared__ float at[256];
    int t = threadIdx.x, b = blockIdx.y, lc = blockIdx.x;
    at[t] = attn[b * LSEQ + lc * 256 + t];
    __syncthreads();
    int col = t * 2;
    const u16* base = featbf + (size_t)(b * LSEQ + lc * 256) * 576 + col;
    float a0 = 0.f, a1 = 0.f;
    #pragma unroll 4
    for (int l = 0; l < 256; l++) {
        unsigned int u = *(const unsigned int*)(base + (size_t)l * 576);
        union { unsigned int i; float f; } lo, hi;
        lo.i = u << 16; hi.i = u & 0xffff0000u;
        float av = at[l];
        a0 += av * lo.f;
        a1 += av * hi.f;
    }
    atomicAdd(&ctx[b * UDIM + col], a0);
    atomicAdd(&ctx[b * UDIM + col + 1], a1);
}

// ---------------- pack / elementwise kernels ----------------
__global__ void pack_acat1_k(const float* __restrict__ Ey, const float* __restrict__ h,
                             const float* __restrict__ ctx, u16* __restrict__ Acat1,
                             const float* __restrict__ bwyh, const float* __restrict__ burh,
                             float* __restrict__ bsum) {
    int b = blockIdx.x, t = threadIdx.x;
    for (int col = t; col < 1280; col += 256) {
        float v = (col < 256) ? Ey[b * 256 + col]
                : (col < 768) ? h[b * 512 + col - 256]
                              : ctx[b * 512 + col - 768];
        Acat1[b * 1280 + col] = f2bf(v);
    }
    if (b == 0) { for (int i = t; i < 512; i += 256) bsum[i] = bwyh[i] + burh[i]; }
}

__global__ void pack_acath_k(const float* __restrict__ Ey, const float* __restrict__ rtp,
                             const float* __restrict__ h, u16* __restrict__ AcatH) {
    int b = blockIdx.x, t = threadIdx.x;
    for (int col = t; col < 768; col += 256) {
        float v;
        if (col < 256) v = Ey[b * 256 + col];
        else {
            int u = col - 256;
            float rt = 1.f / (1.f + __expf(-rtp[b * 512 + u]));
            v = rt * h[b * 512 + u];
        }
        AcatH[b * 768 + col] = f2bf(v);
    }
}

__global__ void pack_ht3_k(const float* __restrict__ ztp, const float* __restrict__ hcp,
                           const float* __restrict__ ccz, const float* __restrict__ bsum,
                           const float* __restrict__ h, const float* __restrict__ ctx,
                           float* __restrict__ ht_out, u16* __restrict__ Acat3) {
    int b = blockIdx.x, t = threadIdx.x;
    for (int u = t; u < 512; u += 256) {
        float z = 1.f / (1.f + __expf(-ztp[b * 512 + u]));
        float hcv = tanhf(hcp[b * 512 + u] + ccz[b * 512 + u] + bsum[u]);
        float v = (1.f - z) * h[b * 512 + u] + z * hcv;
        ht_out[b * 512 + u] = v;
        Acat3[b * 1024 + u] = f2bf(v);
        Acat3[b * 1024 + 512 + u] = f2bf(ctx[b * 512 + u]);
    }
}

__global__ void pack_G_k(const float* __restrict__ Gf32, const float* __restrict__ Ey,
                         u16* __restrict__ Gbf) {
    int b = blockIdx.x, t = threadIdx.x;
    Gbf[b * 256 + t] = f2bf(Gf32[b * 256 + t] + Ey[b * 256 + t]);
}

// ---------------- softmax over V ----------------
__global__ __launch_bounds__(1024) void softmaxV_k(const float* __restrict__ logits,
                                                   float* __restrict__ out) {
    int b = blockIdx.x, t = threadIdx.x;
    __shared__ float sm[16], ss[16];
    const float* lp = logits + (size_t)b * VOC;
    float mx = -1e30f;
    for (int i = t; i < VOC; i += 1024) mx = fmaxf(mx, lp[i]);
    for (int o = 32; o; o >>= 1) mx = fmaxf(mx, __shfl_xor(mx, o, 64));
    if ((t & 63) == 0) sm[t >> 6] = mx;
    __syncthreads();
    if (t < 16) {
        float m2 = sm[t];
        for (int o = 8; o; o >>= 1) m2 = fmaxf(m2, __shfl_xor(m2, o, 16));
        sm[t] = m2;
    }
    __syncthreads();
    mx = sm[0];
    float s = 0.f;
    for (int i = t; i < VOC; i += 1024) s += __expf(lp[i] - mx);
    for (int o = 32; o; o >>= 1) s += __shfl_xor(s, o, 64);
    if ((t & 63) == 0) ss[t >> 6] = s;
    __syncthreads();
    if (t < 16) {
        float s2 = ss[t];
        for (int o = 8; o; o >>= 1) s2 += __shfl_xor(s2, o, 16);
        ss[t] = s2;
    }
    __syncthreads();
    float inv = 1.f / ss[0];
    float* op = out + (size_t)b * VOC;
    for (int i = t; i < VOC; i += 1024) op[i] = __expf(lp[i] - mx) * inv;
}

// ---------------- workspace layout (bytes) ----------------
#define OFF_FEATBF ((size_t)0)           // 150,994,944  (dead after context2_k; logits aliases it)
#define OFF_WTCAT  ((size_t)150994944)
#define OFF_WTWA   ((size_t)151584768)
#define OFF_WTWE   ((size_t)152109056)
#define OFF_WTWO   ((size_t)168493056)
#define OFF_WTHC   ((size_t)184877056)
#define OFF_WTZ    ((size_t)185401344)
#define OFF_WTR    ((size_t)186712064)
#define OFF_WTH    ((size_t)188022784)
#define OFF_PTB    ((size_t)188809216)
#define OFF_PHB    ((size_t)192905216)
// zeroed region start
#define OFF_E      ((size_t)192970752)
#define OFF_HWA    ((size_t)193495040)
#define OFF_EY     ((size_t)193626112)
#define OFF_CTX    ((size_t)193691648)
#define OFF_ZTP    ((size_t)193822720)
#define OFF_RTP    ((size_t)193953792)
#define OFF_CCZ    ((size_t)194084864)
#define OFF_HCP    ((size_t)194215936)
#define OFF_GF32   ((size_t)194347008)
// zeroed region end: 194412544 (total 1,441,792 B = 90112 float4)
#define OFF_ATTNWS ((size_t)194412544)
#define OFF_ACAT1  ((size_t)194936832)
#define OFF_ACATH  ((size_t)195100672)
#define OFF_ACAT3  ((size_t)195198976)
#define OFF_BSUM   ((size_t)195330048)
#define OFF_GBF    ((size_t)195332096)
#define OFF_LOGITS OFF_FEATBF

extern "C" void kernel_launch(void* const* d_in, const int* in_sizes, int n_in,
                              void* d_out, int out_size, void* d_ws, size_t ws_size,
                              hipStream_t stream)
{
    const float* prev_target = (const float*)d_in[0];
    const float* prev_hidden = (const float*)d_in[1];
    const float* features    = (const float*)d_in[2];
    const float* Bmat        = (const float*)d_in[3];
    const float* Wa    = (const float*)d_in[4];
    const float* Ua    = (const float*)d_in[5];
    const float* Va    = (const float*)d_in[6];
    const float* Uf    = (const float*)d_in[7];
    const float* Qk    = (const float*)d_in[8];
    const float* We    = (const float*)d_in[9];
    const float* Wccz  = (const float*)d_in[10];
    const float* Wyz   = (const float*)d_in[11];
    const float* Uhz   = (const float*)d_in[12];
    const float* Wyr   = (const float*)d_in[13];
    const float* Uhr   = (const float*)d_in[14];
    const float* Ccr   = (const float*)d_in[15];
    const float* Wyh   = (const float*)d_in[16];
    const float* b_wyh = (const float*)d_in[17];
    const float* Urh   = (const float*)d_in[18];
    const float* b_urh = (const float*)d_in[19];
    const float* Wo    = (const float*)d_in[20];
    const float* Wh    = (const float*)d_in[21];
    const float* Wc    = (const float*)d_in[22];

    char* w = (char*)d_ws;
    u16*   featbf  = (u16*)(w + OFF_FEATBF);
    u16*   Wt_cat  = (u16*)(w + OFF_WTCAT);
    u16*   Wt_wa   = (u16*)(w + OFF_WTWA);
    u16*   Wt_we   = (u16*)(w + OFF_WTWE);
    u16*   Wt_wo   = (u16*)(w + OFF_WTWO);
    u16*   Wt_hc   = (u16*)(w + OFF_WTHC);
    u16*   Wt_z    = (u16*)(w + OFF_WTZ);
    u16*   Wt_r    = (u16*)(w + OFF_WTR);
    u16*   Wt_h    = (u16*)(w + OFF_WTH);
    u16*   pt_bf   = (u16*)(w + OFF_PTB);
    u16*   ph_bf   = (u16*)(w + OFF_PHB);
    float* e_buf   = (float*)(w + OFF_E);
    float* hWa_buf = (float*)(w + OFF_HWA);
    float* Ey_buf  = (float*)(w + OFF_EY);
    float* ctx_buf = (float*)(w + OFF_CTX);
    float* ztp_buf = (float*)(w + OFF_ZTP);
    float* rtp_buf = (float*)(w + OFF_RTP);
    float* ccz_buf = (float*)(w + OFF_CCZ);
    float* hcp_buf = (float*)(w + OFF_HCP);
    float* Gf32    = (float*)(w + OFF_GF32);
    float* attn_ws = (float*)(w + OFF_ATTNWS);
    u16*   Acat1   = (u16*)(w + OFF_ACAT1);
    u16*   AcatH   = (u16*)(w + OFF_ACATH);
    u16*   Acat3   = (u16*)(w + OFF_ACAT3);
    float* bsum    = (float*)(w + OFF_BSUM);
    u16*   Gbf     = (u16*)(w + OFF_GBF);
    float* logits  = (float*)(w + OFF_LOGITS);

    float* out      = (float*)d_out;
    float* ht_out   = out + (size_t)BZ * VOC;
    float* attn_out = ht_out + (size_t)BZ * UDIM;

    // ---- transpose jobs (Bt[n][k] = W[k][n]) ----
    TArgs ta;
    int cum = 0, ji = 0;
    auto addJob = [&](const float* src, u16* dst, int R, int C, int ld) {
        cum += (R / 32) * (C / 32);
        ta.j[ji].src = src; ta.j[ji].dst = dst;
        ta.j[ji].R = R; ta.j[ji].C = C; ta.j[ji].ld = ld; ta.j[ji].tileEnd = cum;
        ji++;
    };
    addJob(Ua,   Wt_cat + 0,   512, 512, 576);
    addJob(Uf,   Wt_cat + 512,  64, 512, 576);
    addJob(Wa,   Wt_wa,        512, 512, 512);
    addJob(We,   Wt_we,      32000, 256, 32000);
    addJob(Wo,   Wt_wo,        256, 32000, 256);
    addJob(Wh,   Wt_hc + 0,    512, 256, 1024);
    addJob(Wc,   Wt_hc + 512,  512, 256, 1024);
    addJob(Wyz,  Wt_z + 0,     256, 512, 1280);
    addJob(Uhz,  Wt_z + 256,   512, 512, 1280);
    addJob(Wccz, Wt_z + 768,   512, 512, 1280);
    addJob(Wyr,  Wt_r + 0,     256, 512, 1280);
    addJob(Uhr,  Wt_r + 256,   512, 512, 1280);
    addJob(Ccr,  Wt_r + 768,   512, 512, 1280);
    addJob(Wyh,  Wt_h + 0,     256, 512, 768);
    addJob(Urh,  Wt_h + 256,   512, 512, 768);
    ta.nj = ji;

    // ---- small-GEMM job builder ----
    auto mkjob = [](const u16* A, int ldA, const u16* Bt, int ldB, float* C, int ldC,
                    int N, int K, int ckPer, int& c2) {
        GJob g; g.A = A; g.Bt = Bt; g.C = C; g.ldA = ldA; g.ldB = ldB; g.ldC = ldC;
        g.nT = N / 64; g.ckTot = K / 32; g.ckPer = ckPer;
        int ks = (g.ckTot + ckPer - 1) / ckPer;
        c2 += g.nT * ks; g.tileEnd = c2;
        g.store = (ckPer >= g.ckTot) ? 1 : 0;
        return g;
    };

    // 1. zero accumulators
    hipLaunchKernelGGL(zero_k, dim3(352), dim3(256), 0, stream, (float4*)e_buf, 90112);
    // 2. weight transposes
    hipLaunchKernelGGL(transpose_pack, dim3(cum), dim3(256), 0, stream, ta);
    // 3. pack prev_target / prev_hidden
    hipLaunchKernelGGL(pack_misc, dim3(8128), dim3(256), 0, stream,
                       prev_target, prev_hidden, pt_bf, ph_bf);
    // 4. features -> bf16 + fused conv
    hipLaunchKernelGGL(prep_feat_k, dim3(2048), dim3(256), 0, stream,
                       features, Bmat, Qk, featbf);
    // 5. batch A: hWa (64x512,K=512) + Ey (64x256,K=32000)
    {
        GArgs ga; int c2 = 0;
        ga.j[0] = mkjob(ph_bf, 512, Wt_wa, 512, hWa_buf, 512, 512, 512, 4, c2);
        ga.j[1] = mkjob(pt_bf, 32000, Wt_we, 32000, Ey_buf, 256, 256, 32000, 20, c2);
        hipLaunchKernelGGL(gemm_batch_k, dim3(c2), dim3(256), 0, stream, ga);
    }
    // 6. attention scores
    hipLaunchKernelGGL(attn_gemm_k, dim3(1024, 4), dim3(256), 0, stream,
                       featbf, Wt_cat, hWa_buf, Va, e_buf);
    // 7. softmax over L
    hipLaunchKernelGGL(softmaxL_k, dim3(64), dim3(256), 0, stream, e_buf, attn_ws, attn_out);
    // 8. context
    hipLaunchKernelGGL(context2_k, dim3(8, 64), dim3(256), 0, stream,
                       featbf, attn_ws, ctx_buf);
    // 9. Acat1 + bsum
    hipLaunchKernelGGL(pack_acat1_k, dim3(64), dim3(256), 0, stream,
                       Ey_buf, prev_hidden, ctx_buf, Acat1, b_wyh, b_urh, bsum);
    // 10. batch B: zt_pre, rt_pre (K=1280), ccz (K=512)
    {
        GArgs ga; int c2 = 0;
        ga.j[0] = mkjob(Acat1, 1280, Wt_z, 1280, ztp_buf, 512, 512, 1280, 8, c2);
        ga.j[1] = mkjob(Acat1, 1280, Wt_r, 1280, rtp_buf, 512, 512, 1280, 8, c2);
        ga.j[2] = mkjob(Acat1 + 768, 1280, Wt_z + 768, 1280, ccz_buf, 512, 512, 512, 4, c2);
        hipLaunchKernelGGL(gemm_batch_k, dim3(c2), dim3(256), 0, stream, ga);
    }
    // 11. AcatH = [Ey | sigmoid(rt_pre)*h]
    hipLaunchKernelGGL(pack_acath_k, dim3(64), dim3(256), 0, stream,
                       Ey_buf, rtp_buf, prev_hidden, AcatH);
    // 12. batch C: hc_pre (K=768)
    {
        GArgs ga; int c2 = 0;
        ga.j[0] = mkjob(AcatH, 768, Wt_h, 768, hcp_buf, 512, 512, 768, 6, c2);
        hipLaunchKernelGGL(gemm_batch_k, dim3(c2), dim3(256), 0, stream, ga);
    }
    // 13. ht + Acat3
    hipLaunchKernelGGL(pack_ht3_k, dim3(64), dim3(256), 0, stream,
                       ztp_buf, hcp_buf, ccz_buf, bsum, prev_hidden, ctx_buf, ht_out, Acat3);
    // 14. batch D: G = [ht|ctx]@[Wh;Wc] (K=1024)
    {
        GArgs ga; int c2 = 0;
        ga.j[0] = mkjob(Acat3, 1024, Wt_hc, 1024, Gf32, 256, 256, 1024, 8, c2);
        hipLaunchKernelGGL(gemm_batch_k, dim3(c2), dim3(256), 0, stream, ga);
    }
    // 15. Gbf = bf16(G + Ey)
    hipLaunchKernelGGL(pack_G_k, dim3(64), dim3(256), 0, stream, Gf32, Ey_buf, Gbf);
    // 16. batch E: logits = Gbf @ Wo (K=256, direct store)
    {
        GArgs ga; int c2 = 0;
        ga.j[0] = mkjob(Gbf, 256, Wt_wo, 256, logits, 32000, 32000, 256, 8, c2);
        hipLaunchKernelGGL(gemm_batch_k, dim3(c2), dim3(256), 0, stream, ga);
    }
    // 17. softmax over V
    hipLaunchKernelGGL(softmaxV_k, dim3(64), dim3(1024), 0, stream, logits, out);
}